// Round 5
// baseline (431.313 us; speedup 1.0000x reference)
//
#include <hip/hip_runtime.h>
#include <cstdint>
#include <cstddef>

// Problem constants: B=2, T=2048, C=960, NH=24, NKV=6, HD=40
// qkv_out = (24+2*6)*40 = 1440 (padded to 1536), proj N = 960 (padded to 1024)

#define DI __device__ __forceinline__

typedef _Float16 f16x8 __attribute__((ext_vector_type(8)));
typedef _Float16 f16x4 __attribute__((ext_vector_type(4)));
typedef _Float16 f16x2 __attribute__((ext_vector_type(2)));
typedef float f32x4 __attribute__((ext_vector_type(4)));
typedef unsigned short u16;
typedef unsigned int u32;

DI u16 f2h(float f) { _Float16 h = (_Float16)f; return __builtin_bit_cast(u16, h); }
DI float h2f(u16 u) { return (float)__builtin_bit_cast(_Float16, u); }
// cvt_pkrtz returns __fp16x2; bit_cast to our _Float16x2
DI f16x2 pkrtz(float a, float b) { return __builtin_bit_cast(f16x2, __builtin_amdgcn_cvt_pkrtz(a, b)); }

#define MFMA32(a, b, c) __builtin_amdgcn_mfma_f32_16x16x32_f16(a, b, c, 0, 0, 0)
// NOTE: legacy K=16 intrinsic has NO underscore before dtype on this toolchain
#define MFMA16(a, b, c) __builtin_amdgcn_mfma_f32_16x16x16f16(a, b, c, 0, 0, 0)

DI void gload_lds16(const void* g, void* l) {
  __builtin_amdgcn_global_load_lds((const __attribute__((address_space(1))) u32*)g,
                                   (__attribute__((address_space(3))) u32*)l, 16, 0, 0);
}

// ---------------- conversion kernels ----------------

__global__ void cvt_x_kernel(const float* __restrict__ x, u16* __restrict__ o, int n4) {
  int i = blockIdx.x * 256 + threadIdx.x;
  if (i >= n4) return;
  float4 v = ((const float4*)x)[i];
  ushort4 r;
  r.x = f2h(v.x); r.y = f2h(v.y); r.z = f2h(v.z); r.w = f2h(v.w);
  ((ushort4*)o)[i] = r;
}

__global__ void cvt_w_kernel(const float* __restrict__ w, const float* __restrict__ bias,
                             u16* __restrict__ o, float* __restrict__ bo,
                             int rows_in, int rows_out, int cols) {
  int i = blockIdx.x * 256 + threadIdx.x;
  int c4 = cols >> 2;
  int total = rows_out * c4;
  if (i < total) {
    int row = i / c4, c = (i - row * c4) * 4;
    ushort4 r;
    if (row < rows_in) {
      float4 v = *(const float4*)&w[(size_t)row * cols + c];
      r.x = f2h(v.x); r.y = f2h(v.y); r.z = f2h(v.z); r.w = f2h(v.w);
    } else {
      r.x = r.y = r.z = r.w = 0;
    }
    *(ushort4*)&o[(size_t)row * cols + c] = r;
  }
  if (bo != nullptr && i < rows_out) bo[i] = (i < rows_in) ? bias[i] : 0.f;
}

// ---------------- GEMM: C[M][N] = A[M][K] @ B[N][K]^T + bias ----------------
template <int MODE>
__global__ __launch_bounds__(256) void gemm_bt(const u16* __restrict__ A, const u16* __restrict__ Bw,
                                               const float* __restrict__ bias, void* __restrict__ outp,
                                               int K, int Npad, int Nstore) {
  __shared__ u16 As[128 * 32];
  __shared__ u16 Bs[128 * 32];
  const int tid = threadIdx.x;
  const int l = tid & 63, w = tid >> 6;
  const int bm = blockIdx.x, bn = blockIdx.y;
  const int wm = w >> 1, wn = w & 1;
  const int la = l & 15, lg = l >> 4;

  const u16* ga = A + (size_t)(bm * 128 + (tid >> 2)) * K + (tid & 3) * 8;
  const u16* gb = Bw + (size_t)(bn * 128 + (tid >> 2)) * K + (tid & 3) * 8;
  void* lA = (void*)(As + (size_t)w * 512);
  void* lB = (void*)(Bs + (size_t)w * 512);

  f32x4 acc[4][4] = {};

  for (int k0 = 0; k0 < K; k0 += 32) {
    __syncthreads();
    gload_lds16(ga, lA);
    gload_lds16(ga + (size_t)64 * K, (char*)lA + 4096);
    gload_lds16(gb, lB);
    gload_lds16(gb + (size_t)64 * K, (char*)lB + 4096);
    ga += 32; gb += 32;
    __syncthreads();
    f16x8 af[4], bf[4];
#pragma unroll
    for (int i = 0; i < 4; i++)
      af[i] = *(const f16x8*)&As[(wm * 64 + i * 16 + la) * 32 + lg * 8];
#pragma unroll
    for (int j = 0; j < 4; j++)
      bf[j] = *(const f16x8*)&Bs[(wn * 64 + j * 16 + la) * 32 + lg * 8];
#pragma unroll
    for (int i = 0; i < 4; i++)
#pragma unroll
      for (int j = 0; j < 4; j++)
        acc[i][j] = MFMA32(af[i], bf[j], acc[i][j]);
  }

  const int rowb = bm * 128 + wm * 64 + lg * 4;
  const int colb = bn * 128 + wn * 64 + la;
#pragma unroll
  for (int j = 0; j < 4; j++) {
    int col = colb + j * 16;
    float bv = (MODE == 1 && col >= Nstore) ? 0.f : bias[col];
#pragma unroll
    for (int i = 0; i < 4; i++) {
#pragma unroll
      for (int r = 0; r < 4; r++) {
        int row = rowb + i * 16 + r;
        float v = acc[i][j][r] + bv;
        if (MODE == 0) {
          ((u16*)outp)[(size_t)row * Npad + col] = f2h(v);
        } else {
          if (col < Nstore) ((float*)outp)[(size_t)row * Nstore + col] = v;
        }
      }
    }
  }
}

// ---------------- RoPE + scatter ----------------
// qkv fp16 [4096][1536] -> q_pad [2][24][2048][64] (rope'd, * log2e/sqrt(40), d>=40 zero)
//                          k_pad [2][6][2048][64]  (rope'd, d>=40 zero)
//                          v_t   [2][6][64][2048]  (transposed, d<40; d in 40..47 zeroed)
// Q carries log2e so attention softmax can use exp2 (v_exp_f32) directly.
__global__ __launch_bounds__(256) void rope_scatter(const u16* __restrict__ qkv,
                                                    u16* __restrict__ qp, u16* __restrict__ kp,
                                                    u16* __restrict__ vt) {
  const int m = blockIdx.x;  // b*2048 + t
  const int b = m >> 11, t = m & 2047;
  const size_t qkvrow = (size_t)m * 1536;
  for (int i = threadIdx.x; i < 1128; i += 256) {
    if (i < 960) {
      int head = i >> 5, pp = i & 31;  // 30 heads x 32 pair-slots (pad to 64 dims)
      bool isq = head < 24;
      int hh = isq ? head : head - 24;
      u16* dst = isq ? (qp + (((size_t)b * 24 + hh) * 2048 + t) * 64)
                     : (kp + (((size_t)b * 6 + hh) * 2048 + t) * 64);
      if (pp < 20) {
        int col = isq ? (head * 40 + 2 * pp) : (960 + hh * 40 + 2 * pp);
        float x1 = h2f(qkv[qkvrow + col]);
        float x2 = h2f(qkv[qkvrow + col + 1]);
        float inv = powf(10000.f, -(float)pp * 0.05f);  // 10000^(-2*pp/40)
        float th = (float)t * inv;
        float sn = sinf(th), cs = cosf(th);
        float r1 = x1 * cs - x2 * sn;
        float r2 = x1 * sn + x2 * cs;
        if (isq) { r1 *= 0.2281099142f; r2 *= 0.2281099142f; }  // log2e / sqrt(40)
        dst[2 * pp] = f2h(r1);
        dst[2 * pp + 1] = f2h(r2);
      } else {
        dst[2 * pp] = 0;
        dst[2 * pp + 1] = 0;
      }
    } else if (i < 1080) {
      int j = i - 960;  // 6 heads x 20 pairs of V
      int head = j / 20, pp = j - head * 20;
      int col = 1200 + head * 40 + 2 * pp;
      size_t vb = (((size_t)b * 6 + head) * 64 + 2 * pp) * 2048 + t;
      vt[vb] = qkv[qkvrow + col];
      vt[vb + 2048] = qkv[qkvrow + col + 1];
    } else {
      int j = i - 1080;  // zero V pad rows d=40..47 (read by PV d-tile 2)
      int head = j >> 3, d = 40 + (j & 7);
      vt[(((size_t)b * 6 + head) * 64 + d) * 2048 + t] = 0;
    }
  }
}

// ---------------- flash attention (causal, GQA), swapped-operand ----------------
// One q-tile (16 rows) per wave, 2 waves (adjacent tiles) per block, tiles
// dispatched longest-first. K register-double-buffered (prefetch chunk c+1
// during chunk c). Only the final chunk needs causal masking. Softmax in exp2
// domain (Q pre-scaled by log2e), defer-max rescale (THR=5 -> P<=32, fp16-safe).
__global__ __launch_bounds__(128) void attn_kernel(const u16* __restrict__ qp,
                                                   const u16* __restrict__ kp,
                                                   const u16* __restrict__ vt,
                                                   u16* __restrict__ ao) {
  const int tid = threadIdx.x, l = tid & 63, w = tid >> 6;
  const int la = l & 15, lg = l >> 4;
  const int bid = blockIdx.x;
  const int tile = 127 - ((bid & 63) * 2 + w);  // longest first
  const int bh = bid >> 6;
  const int b = bh / 24, h = bh - b * 24, hk = h >> 2;

  const u16* kg = kp + ((size_t)b * 6 + hk) * 2048 * 64 + la * 64 + lg * 8;
  const u16* vg = vt + ((size_t)b * 6 + hk) * 64 * 2048 + la * 2048 + lg * 4;

  const int q0 = tile * 16, qg = q0 + la;
  const u16* qrow = qp + (((size_t)b * 24 + h) * 2048 + qg) * 64 + lg * 8;
  f16x8 qf0 = *(const f16x8*)qrow;
  f16x8 qf1 = *(const f16x8*)(qrow + 32);

  f32x4 acc0 = {}, acc1 = {}, acc2 = {};
  float m = -1e30f, lsum = 0.f;
  const int nch = (tile >> 1) + 1;   // 32-kv chunks
  const int UNM = nch - 1;           // fully-unmasked chunk count

  f16x8 kA0a, kA0b, kA1a, kA1b, kB0a, kB0b, kB1a, kB1b;

#define LOADK(P, c) do { const u16* kc_ = kg + (size_t)(c) * 2048; \
    P##0a = *(const f16x8*)kc_;          P##0b = *(const f16x8*)(kc_ + 32); \
    P##1a = *(const f16x8*)(kc_ + 1024); P##1b = *(const f16x8*)(kc_ + 1056); } while (0)

#define COMPUTE(P, c, MASKED) do { \
    const int kv0_ = (c) * 32; \
    const u16* vc_ = vg + kv0_; \
    f16x4 v00 = *(const f16x4*)vc_,                         v01 = *(const f16x4*)(vc_ + 16); \
    f16x4 v10 = *(const f16x4*)(vc_ + (size_t)16 * 2048),   v11 = *(const f16x4*)(vc_ + (size_t)16 * 2048 + 16); \
    f16x4 v20 = *(const f16x4*)(vc_ + (size_t)32 * 2048),   v21 = *(const f16x4*)(vc_ + (size_t)32 * 2048 + 16); \
    f32x4 z_ = {0.f, 0.f, 0.f, 0.f}; \
    f32x4 s0 = MFMA32(P##0a, qf0, z_); s0 = MFMA32(P##0b, qf1, s0); \
    f32x4 s1 = MFMA32(P##1a, qf0, z_); s1 = MFMA32(P##1b, qf1, s1); \
    if (MASKED) { \
      _Pragma("unroll") for (int r = 0; r < 4; r++) { \
        int kva_ = kv0_ + lg * 4 + r; \
        if (kva_ > qg) s0[r] = -1e30f; \
        if (kva_ + 16 > qg) s1[r] = -1e30f; \
      } \
    } \
    float pm = fmaxf(fmaxf(fmaxf(s0[0], s0[1]), fmaxf(s0[2], s0[3])), \
                     fmaxf(fmaxf(s1[0], s1[1]), fmaxf(s1[2], s1[3]))); \
    pm = fmaxf(pm, __shfl_xor(pm, 16)); \
    pm = fmaxf(pm, __shfl_xor(pm, 32)); \
    if (!__all(pm <= m + 5.f)) { \
      float mn_ = fmaxf(m, pm); \
      float al_ = exp2f(m - mn_); \
      m = mn_; lsum *= al_; \
      _Pragma("unroll") for (int r = 0; r < 4; r++) { acc0[r] *= al_; acc1[r] *= al_; acc2[r] *= al_; } \
    } \
    float ps = 0.f; \
    _Pragma("unroll") for (int r = 0; r < 4; r++) { \
      s0[r] = exp2f(s0[r] - m); s1[r] = exp2f(s1[r] - m); ps += s0[r] + s1[r]; } \
    ps += __shfl_xor(ps, 16); \
    ps += __shfl_xor(ps, 32); \
    lsum += ps; \
    f16x2 pa_ = pkrtz(s0[0], s0[1]); \
    f16x2 pb_ = pkrtz(s0[2], s0[3]); \
    f16x2 pc_ = pkrtz(s1[0], s1[1]); \
    f16x2 pd_ = pkrtz(s1[2], s1[3]); \
    f16x4 p0 = __builtin_shufflevector(pa_, pb_, 0, 1, 2, 3); \
    f16x4 p1 = __builtin_shufflevector(pc_, pd_, 0, 1, 2, 3); \
    acc0 = MFMA16(v00, p0, acc0); acc0 = MFMA16(v01, p1, acc0); \
    acc1 = MFMA16(v10, p0, acc1); acc1 = MFMA16(v11, p1, acc1); \
    acc2 = MFMA16(v20, p0, acc2); acc2 = MFMA16(v21, p1, acc2); \
  } while (0)

  LOADK(kA, 0);
  int c = 0;
  for (; c + 1 < UNM; c += 2) {
    LOADK(kB, c + 1);
    COMPUTE(kA, c, false);
    LOADK(kA, c + 2);
    COMPUTE(kB, c + 1, false);
  }
  if (c < UNM) {
    LOADK(kB, c + 1);
    COMPUTE(kA, c, false);
    COMPUTE(kB, c + 1, true);
  } else {
    COMPUTE(kA, c, true);
  }
#undef LOADK
#undef COMPUTE

  // epilogue: lane owns q=q0+la, d = dt*16 + lg*4 + r
  const float inv = 1.f / lsum;
  u16* orow = ao + ((size_t)b * 2048 + q0 + la) * 960 + h * 40;
#pragma unroll
  for (int r = 0; r < 4; r++) {
    int d0 = lg * 4 + r;
    orow[d0] = f2h(acc0[r] * inv);
    orow[d0 + 16] = f2h(acc1[r] * inv);
    if (d0 + 32 < 40) orow[d0 + 32] = f2h(acc2[r] * inv);
  }
}

// ---------------- launch ----------------

extern "C" void kernel_launch(void* const* d_in, const int* in_sizes, int n_in,
                              void* d_out, int out_size, void* d_ws, size_t ws_size,
                              hipStream_t stream) {
  const float* x = (const float*)d_in[0];      // [2][2048][960]
  const float* Wqkv = (const float*)d_in[1];   // [1440][960]
  const float* bqkv = (const float*)d_in[2];   // [1440]
  const float* Wproj = (const float*)d_in[3];  // [960][960]
  const float* bproj = (const float*)d_in[4];  // [960]
  float* out = (float*)d_out;                  // [4096][960] fp32

  // workspace layout (~52 MB)
  char* ws = (char*)d_ws;
  u16* xb = (u16*)ws;                                // 4096*960
  u16* wqkvb = xb + (size_t)4096 * 960;              // 1536*960
  u16* wprojb = wqkvb + (size_t)1536 * 960;          // 1024*960
  float* bqp = (float*)(wprojb + (size_t)1024 * 960);// 1536
  u16* qkvb = (u16*)(bqp + 1536);                    // 4096*1536
  u16* qp = qkvb + (size_t)4096 * 1536;              // 2*24*2048*64
  u16* kp = qp + (size_t)2 * 24 * 2048 * 64;         // 2*6*2048*64
  u16* vt = kp + (size_t)2 * 6 * 2048 * 64;          // 2*6*64*2048
  u16* ao = vt + (size_t)2 * 6 * 64 * 2048;          // 4096*960

  // converts
  cvt_x_kernel<<<3840, 256, 0, stream>>>(x, xb, 4096 * 960 / 4);
  cvt_w_kernel<<<1440, 256, 0, stream>>>(Wqkv, bqkv, wqkvb, bqp, 1440, 1536, 960);
  cvt_w_kernel<<<960, 256, 0, stream>>>(Wproj, nullptr, wprojb, nullptr, 960, 1024, 960);

  // QKV projection: [4096][1536] = x @ Wqkv^T + b
  gemm_bt<0><<<dim3(32, 12), 256, 0, stream>>>(xb, wqkvb, bqp, qkvb, 960, 1536, 1536);

  // RoPE + scatter to attention layouts
  rope_scatter<<<4096, 256, 0, stream>>>(qkvb, qp, kp, vt);

  // flash attention: 48 bh x 64 tile-pairs, 2 waves/block (1 tile each)
  attn_kernel<<<3072, 128, 0, stream>>>(qp, kp, vt, ao);

  // output projection: [4096][960] = attn @ Wproj^T + b (fp32 out)
  gemm_bt<1><<<dim3(32, 8), 256, 0, stream>>>(ao, wprojb, bproj, out, 960, 1024, 960);
}

// Round 6
// 242.137 us; speedup vs baseline: 1.7813x; 1.7813x over previous
//
#include <hip/hip_runtime.h>
#include <cstdint>
#include <cstddef>

// Problem constants: B=2, T=2048, C=960, NH=24, NKV=6, HD=40
// qkv_out = 1440 (padded to 1536 for GEMM), proj N = 960 (padded to 1024)
// Attention layouts use D padded to 48 (40 real + 8 zero).

#define DI __device__ __forceinline__

typedef _Float16 f16x8 __attribute__((ext_vector_type(8)));
typedef _Float16 f16x4 __attribute__((ext_vector_type(4)));
typedef _Float16 f16x2 __attribute__((ext_vector_type(2)));
typedef float f32x4 __attribute__((ext_vector_type(4)));
typedef unsigned short u16;
typedef unsigned int u32;

DI u16 f2h(float f) { _Float16 h = (_Float16)f; return __builtin_bit_cast(u16, h); }
DI float h2f(u16 u) { return (float)__builtin_bit_cast(_Float16, u); }
DI f16x2 pkrtz(float a, float b) { return __builtin_bit_cast(f16x2, __builtin_amdgcn_cvt_pkrtz(a, b)); }

#define MFMA32(a, b, c) __builtin_amdgcn_mfma_f32_16x16x32_f16(a, b, c, 0, 0, 0)
#define MFMA16(a, b, c) __builtin_amdgcn_mfma_f32_16x16x16f16(a, b, c, 0, 0, 0)

DI void gload_lds16(const void* g, void* l) {
  __builtin_amdgcn_global_load_lds((const __attribute__((address_space(1))) u32*)g,
                                   (__attribute__((address_space(3))) u32*)l, 16, 0, 0);
}

// ---------------- conversion kernels ----------------

__global__ void cvt_x_kernel(const float* __restrict__ x, u16* __restrict__ o, int n4) {
  int i = blockIdx.x * 256 + threadIdx.x;
  if (i >= n4) return;
  float4 v = ((const float4*)x)[i];
  ushort4 r;
  r.x = f2h(v.x); r.y = f2h(v.y); r.z = f2h(v.z); r.w = f2h(v.w);
  ((ushort4*)o)[i] = r;
}

__global__ void cvt_w_kernel(const float* __restrict__ w, const float* __restrict__ bias,
                             u16* __restrict__ o, float* __restrict__ bo,
                             int rows_in, int rows_out, int cols) {
  int i = blockIdx.x * 256 + threadIdx.x;
  int c4 = cols >> 2;
  int total = rows_out * c4;
  if (i < total) {
    int row = i / c4, c = (i - row * c4) * 4;
    ushort4 r;
    if (row < rows_in) {
      float4 v = *(const float4*)&w[(size_t)row * cols + c];
      r.x = f2h(v.x); r.y = f2h(v.y); r.z = f2h(v.z); r.w = f2h(v.w);
    } else {
      r.x = r.y = r.z = r.w = 0;
    }
    *(ushort4*)&o[(size_t)row * cols + c] = r;
  }
  if (bo != nullptr && i < rows_out) bo[i] = (i < rows_in) ? bias[i] : 0.f;
}

// ---------------- GEMM: C[M][N] = A[M][K] @ B[N][K]^T + bias ----------------
template <int MODE>
__global__ __launch_bounds__(256) void gemm_bt(const u16* __restrict__ A, const u16* __restrict__ Bw,
                                               const float* __restrict__ bias, void* __restrict__ outp,
                                               int K, int Npad, int Nstore) {
  __shared__ u16 As[128 * 32];
  __shared__ u16 Bs[128 * 32];
  const int tid = threadIdx.x;
  const int l = tid & 63, w = tid >> 6;
  const int bm = blockIdx.x, bn = blockIdx.y;
  const int wm = w >> 1, wn = w & 1;
  const int la = l & 15, lg = l >> 4;

  const u16* ga = A + (size_t)(bm * 128 + (tid >> 2)) * K + (tid & 3) * 8;
  const u16* gb = Bw + (size_t)(bn * 128 + (tid >> 2)) * K + (tid & 3) * 8;
  void* lA = (void*)(As + (size_t)w * 512);
  void* lB = (void*)(Bs + (size_t)w * 512);

  f32x4 acc[4][4] = {};

  for (int k0 = 0; k0 < K; k0 += 32) {
    __syncthreads();
    gload_lds16(ga, lA);
    gload_lds16(ga + (size_t)64 * K, (char*)lA + 4096);
    gload_lds16(gb, lB);
    gload_lds16(gb + (size_t)64 * K, (char*)lB + 4096);
    ga += 32; gb += 32;
    __syncthreads();
    f16x8 af[4], bf[4];
#pragma unroll
    for (int i = 0; i < 4; i++)
      af[i] = *(const f16x8*)&As[(wm * 64 + i * 16 + la) * 32 + lg * 8];
#pragma unroll
    for (int j = 0; j < 4; j++)
      bf[j] = *(const f16x8*)&Bs[(wn * 64 + j * 16 + la) * 32 + lg * 8];
#pragma unroll
    for (int i = 0; i < 4; i++)
#pragma unroll
      for (int j = 0; j < 4; j++)
        acc[i][j] = MFMA32(af[i], bf[j], acc[i][j]);
  }

  const int rowb = bm * 128 + wm * 64 + lg * 4;
  const int colb = bn * 128 + wn * 64 + la;
#pragma unroll
  for (int j = 0; j < 4; j++) {
    int col = colb + j * 16;
    float bv = (MODE == 1 && col >= Nstore) ? 0.f : bias[col];
#pragma unroll
    for (int i = 0; i < 4; i++) {
#pragma unroll
      for (int r = 0; r < 4; r++) {
        int row = rowb + i * 16 + r;
        float v = acc[i][j][r] + bv;
        if (MODE == 0) {
          ((u16*)outp)[(size_t)row * Npad + col] = f2h(v);
        } else {
          if (col < Nstore) ((float*)outp)[(size_t)row * Nstore + col] = v;
        }
      }
    }
  }
}

// ---------------- RoPE + scatter ----------------
// qkv fp16 [4096][1536] -> q [2][24][2048][48] (rope'd, * log2e/sqrt(40), d>=40 zero)
//                          k [2][6][2048][48]  (rope'd, d>=40 zero)
//                          v^T [2][6][48][2048] (transposed; rows 40..47 zero)
__global__ __launch_bounds__(256) void rope_scatter(const u16* __restrict__ qkv,
                                                    u16* __restrict__ qp, u16* __restrict__ kp,
                                                    u16* __restrict__ vt) {
  const int m = blockIdx.x;  // b*2048 + t
  const int b = m >> 11, t = m & 2047;
  const size_t qkvrow = (size_t)m * 1536;
  for (int i = threadIdx.x; i < 864; i += 256) {
    if (i < 720) {
      int head = i / 24, pp = i - head * 24;  // 30 heads x 24 pair-slots (48 dims)
      bool isq = head < 24;
      int hh = isq ? head : head - 24;
      u16* dst = isq ? (qp + (((size_t)b * 24 + hh) * 2048 + t) * 48)
                     : (kp + (((size_t)b * 6 + hh) * 2048 + t) * 48);
      if (pp < 20) {
        int col = isq ? (head * 40 + 2 * pp) : (960 + hh * 40 + 2 * pp);
        float x1 = h2f(qkv[qkvrow + col]);
        float x2 = h2f(qkv[qkvrow + col + 1]);
        float inv = powf(10000.f, -(float)pp * 0.05f);  // 10000^(-2*pp/40)
        float th = (float)t * inv;
        float sn = sinf(th), cs = cosf(th);
        float r1 = x1 * cs - x2 * sn;
        float r2 = x1 * sn + x2 * cs;
        if (isq) { r1 *= 0.2281099142f; r2 *= 0.2281099142f; }  // log2e / sqrt(40)
        dst[2 * pp] = f2h(r1);
        dst[2 * pp + 1] = f2h(r2);
      } else {
        dst[2 * pp] = 0;
        dst[2 * pp + 1] = 0;
      }
    } else {
      int j = i - 720;  // 6 heads x 24 pair-slots of V^T
      int head = j / 24, pp = j - head * 24;
      size_t vb = (((size_t)b * 6 + head) * 48 + 2 * pp) * 2048 + t;
      if (pp < 20) {
        int col = 1200 + head * 40 + 2 * pp;
        vt[vb] = qkv[qkvrow + col];
        vt[vb + 2048] = qkv[qkvrow + col + 1];
      } else {
        vt[vb] = 0;
        vt[vb + 2048] = 0;
      }
    }
  }
}

// ---------------- flash attention (causal, GQA), swapped-operand, 2 heads/wave --
// Wave = 2 q-heads (GQA pair) x 16 q-rows (one window). K frags loaded once per
// chunk serve both heads (4 independent QK MFMA chains -> ILP); V frags shared
// by both heads' PV. Block = 4 waves (2 head-pairs x 2 adjacent windows, same
// b,hk) so K/V global reads hit L1. D packed to 48: QK = MFMA32 + MFMA16.
// Exactly one masked chunk (the last). K register double-buffered.
__global__ __launch_bounds__(256) void attn_kernel(const u16* __restrict__ qp,
                                                   const u16* __restrict__ kp,
                                                   const u16* __restrict__ vt,
                                                   u16* __restrict__ ao) {
  const int tid = threadIdx.x, l = tid & 63, wv = tid >> 6;
  const int la = l & 15, lg = l >> 4;
  const int bid = blockIdx.x;
  const int bhk = bid >> 6, blk = bid & 63;
  const int b = bhk / 6, hk = bhk - b * 6;
  const int win = (126 - 2 * blk) + (wv >> 1);  // descending: long windows first
  const int h0 = hk * 4 + (wv & 1) * 2;         // this wave's head pair

  const int q0 = win * 16, qg = q0 + la;
  const u16* kg = kp + ((size_t)b * 6 + hk) * 2048 * 48;
  const u16* vg = vt + ((size_t)b * 6 + hk) * 48 * 2048;

  const u16* qra = qp + (((size_t)b * 24 + h0) * 2048 + qg) * 48;
  const u16* qrb = qra + (size_t)2048 * 48;
  f16x8 qa8 = *(const f16x8*)(qra + lg * 8);
  f16x4 qa4 = *(const f16x4*)(qra + 32 + lg * 4);
  f16x8 qb8 = *(const f16x8*)(qrb + lg * 8);
  f16x4 qb4 = *(const f16x4*)(qrb + 32 + lg * 4);

  f32x4 accA0 = {}, accA1 = {}, accA2 = {};
  f32x4 accB0 = {}, accB1 = {}, accB2 = {};
  float mA = -1e30f, mB = -1e30f, lsA = 0.f, lsB = 0.f;
  const int nch = (q0 >> 5) + 1;  // 32-kv chunks; last one masked

  f16x8 kA08, kA18, kB08, kB18;
  f16x4 kA04, kA14, kB04, kB14;

#define LOADK(P, c) do { \
    const u16* kr0_ = kg + ((size_t)((c) * 32) + la) * 48; \
    P##08 = *(const f16x8*)(kr0_ + lg * 8); \
    P##04 = *(const f16x4*)(kr0_ + 32 + lg * 4); \
    const u16* kr1_ = kr0_ + 16 * 48; \
    P##18 = *(const f16x8*)(kr1_ + lg * 8); \
    P##14 = *(const f16x4*)(kr1_ + 32 + lg * 4); \
  } while (0)

#define SOFTMAX(s0, s1, mrun, lrun, a0, a1, a2, p0, p1) do { \
    float pm_ = fmaxf(fmaxf(fmaxf(s0[0], s0[1]), fmaxf(s0[2], s0[3])), \
                      fmaxf(fmaxf(s1[0], s1[1]), fmaxf(s1[2], s1[3]))); \
    pm_ = fmaxf(pm_, __shfl_xor(pm_, 16)); \
    pm_ = fmaxf(pm_, __shfl_xor(pm_, 32)); \
    if (!__all(pm_ <= mrun + 5.f)) { \
      float mn_ = fmaxf(mrun, pm_); \
      float al_ = exp2f(mrun - mn_); \
      mrun = mn_; lrun *= al_; \
      _Pragma("unroll") for (int r = 0; r < 4; r++) { a0[r] *= al_; a1[r] *= al_; a2[r] *= al_; } \
    } \
    float ps_ = 0.f; \
    _Pragma("unroll") for (int r = 0; r < 4; r++) { \
      s0[r] = exp2f(s0[r] - mrun); s1[r] = exp2f(s1[r] - mrun); ps_ += s0[r] + s1[r]; } \
    ps_ += __shfl_xor(ps_, 16); \
    ps_ += __shfl_xor(ps_, 32); \
    lrun += ps_; \
    p0 = __builtin_shufflevector(pkrtz(s0[0], s0[1]), pkrtz(s0[2], s0[3]), 0, 1, 2, 3); \
    p1 = __builtin_shufflevector(pkrtz(s1[0], s1[1]), pkrtz(s1[2], s1[3]), 0, 1, 2, 3); \
  } while (0)

#define COMPUTE(P, c, MASKED) do { \
    const int kv0_ = (c) * 32; \
    const u16* vb_ = vg + (size_t)la * 2048 + kv0_ + lg * 4; \
    f16x4 v00 = *(const f16x4*)(vb_); \
    f16x4 v01 = *(const f16x4*)(vb_ + 16); \
    f16x4 v10 = *(const f16x4*)(vb_ + (size_t)16 * 2048); \
    f16x4 v11 = *(const f16x4*)(vb_ + (size_t)16 * 2048 + 16); \
    f16x4 v20 = *(const f16x4*)(vb_ + (size_t)32 * 2048); \
    f16x4 v21 = *(const f16x4*)(vb_ + (size_t)32 * 2048 + 16); \
    f32x4 z_ = {0.f, 0.f, 0.f, 0.f}; \
    f32x4 sA0 = MFMA32(P##08, qa8, z_); sA0 = MFMA16(P##04, qa4, sA0); \
    f32x4 sA1 = MFMA32(P##18, qa8, z_); sA1 = MFMA16(P##14, qa4, sA1); \
    f32x4 sB0 = MFMA32(P##08, qb8, z_); sB0 = MFMA16(P##04, qb4, sB0); \
    f32x4 sB1 = MFMA32(P##18, qb8, z_); sB1 = MFMA16(P##14, qb4, sB1); \
    if (MASKED) { \
      _Pragma("unroll") for (int r = 0; r < 4; r++) { \
        int kva_ = kv0_ + lg * 4 + r; \
        if (kva_ > qg) { sA0[r] = -1e30f; sB0[r] = -1e30f; } \
        if (kva_ + 16 > qg) { sA1[r] = -1e30f; sB1[r] = -1e30f; } \
      } \
    } \
    f16x4 pA0, pA1, pB0, pB1; \
    SOFTMAX(sA0, sA1, mA, lsA, accA0, accA1, accA2, pA0, pA1); \
    SOFTMAX(sB0, sB1, mB, lsB, accB0, accB1, accB2, pB0, pB1); \
    accA0 = MFMA16(v00, pA0, accA0); accA0 = MFMA16(v01, pA1, accA0); \
    accA1 = MFMA16(v10, pA0, accA1); accA1 = MFMA16(v11, pA1, accA1); \
    accA2 = MFMA16(v20, pA0, accA2); accA2 = MFMA16(v21, pA1, accA2); \
    accB0 = MFMA16(v00, pB0, accB0); accB0 = MFMA16(v01, pB1, accB0); \
    accB1 = MFMA16(v10, pB0, accB1); accB1 = MFMA16(v11, pB1, accB1); \
    accB2 = MFMA16(v20, pB0, accB2); accB2 = MFMA16(v21, pB1, accB2); \
  } while (0)

  LOADK(kA, 0);
  int c = 0;
  for (; c + 2 < nch; c += 2) {
    LOADK(kB, c + 1);
    COMPUTE(kA, c, false);
    LOADK(kA, c + 2);
    COMPUTE(kB, c + 1, false);
  }
  if (c + 2 == nch) {
    LOADK(kB, c + 1);
    COMPUTE(kA, c, false);
    COMPUTE(kB, c + 1, true);
  } else {
    COMPUTE(kA, c, true);
  }
#undef LOADK
#undef SOFTMAX
#undef COMPUTE

  // epilogue: lane owns q=q0+la, d = dt*16 + lg*4 + r; packed f16x4 stores
  u16* orow = ao + ((size_t)b * 2048 + qg) * 960 + h0 * 40;
  {
    float inv = 1.f / lsA;
    f16x4 o0 = __builtin_shufflevector(pkrtz(accA0[0] * inv, accA0[1] * inv),
                                       pkrtz(accA0[2] * inv, accA0[3] * inv), 0, 1, 2, 3);
    f16x4 o1 = __builtin_shufflevector(pkrtz(accA1[0] * inv, accA1[1] * inv),
                                       pkrtz(accA1[2] * inv, accA1[3] * inv), 0, 1, 2, 3);
    f16x4 o2 = __builtin_shufflevector(pkrtz(accA2[0] * inv, accA2[1] * inv),
                                       pkrtz(accA2[2] * inv, accA2[3] * inv), 0, 1, 2, 3);
    *(f16x4*)(orow + lg * 4) = o0;
    *(f16x4*)(orow + 16 + lg * 4) = o1;
    if (lg < 2) *(f16x4*)(orow + 32 + lg * 4) = o2;
  }
  {
    float inv = 1.f / lsB;
    f16x4 o0 = __builtin_shufflevector(pkrtz(accB0[0] * inv, accB0[1] * inv),
                                       pkrtz(accB0[2] * inv, accB0[3] * inv), 0, 1, 2, 3);
    f16x4 o1 = __builtin_shufflevector(pkrtz(accB1[0] * inv, accB1[1] * inv),
                                       pkrtz(accB1[2] * inv, accB1[3] * inv), 0, 1, 2, 3);
    f16x4 o2 = __builtin_shufflevector(pkrtz(accB2[0] * inv, accB2[1] * inv),
                                       pkrtz(accB2[2] * inv, accB2[3] * inv), 0, 1, 2, 3);
    *(f16x4*)(orow + 40 + lg * 4) = o0;
    *(f16x4*)(orow + 56 + lg * 4) = o1;
    if (lg < 2) *(f16x4*)(orow + 72 + lg * 4) = o2;
  }
}

// ---------------- launch ----------------

extern "C" void kernel_launch(void* const* d_in, const int* in_sizes, int n_in,
                              void* d_out, int out_size, void* d_ws, size_t ws_size,
                              hipStream_t stream) {
  const float* x = (const float*)d_in[0];      // [2][2048][960]
  const float* Wqkv = (const float*)d_in[1];   // [1440][960]
  const float* bqkv = (const float*)d_in[2];   // [1440]
  const float* Wproj = (const float*)d_in[3];  // [960][960]
  const float* bproj = (const float*)d_in[4];  // [960]
  float* out = (float*)d_out;                  // [4096][960] fp32

  // workspace layout (~47 MB)
  char* ws = (char*)d_ws;
  u16* xb = (u16*)ws;                                // 4096*960
  u16* wqkvb = xb + (size_t)4096 * 960;              // 1536*960
  u16* wprojb = wqkvb + (size_t)1536 * 960;          // 1024*960
  float* bqp = (float*)(wprojb + (size_t)1024 * 960);// 1536
  u16* qkvb = (u16*)(bqp + 1536);                    // 4096*1536
  u16* qp = qkvb + (size_t)4096 * 1536;              // 2*24*2048*48
  u16* kp = qp + (size_t)2 * 24 * 2048 * 48;         // 2*6*2048*48
  u16* vt = kp + (size_t)2 * 6 * 2048 * 48;          // 2*6*48*2048
  u16* ao = vt + (size_t)2 * 6 * 48 * 2048;          // 4096*960

  // converts
  cvt_x_kernel<<<3840, 256, 0, stream>>>(x, xb, 4096 * 960 / 4);
  cvt_w_kernel<<<1440, 256, 0, stream>>>(Wqkv, bqkv, wqkvb, bqp, 1440, 1536, 960);
  cvt_w_kernel<<<960, 256, 0, stream>>>(Wproj, nullptr, wprojb, nullptr, 960, 1024, 960);

  // QKV projection: [4096][1536] = x @ Wqkv^T + b
  gemm_bt<0><<<dim3(32, 12), 256, 0, stream>>>(xb, wqkvb, bqp, qkvb, 960, 1536, 1536);

  // RoPE + scatter to attention layouts (D=48)
  rope_scatter<<<4096, 256, 0, stream>>>(qkvb, qp, kp, vt);

  // flash attention: 12 (b,hk) x 64 window-pair blocks, 4 waves each
  attn_kernel<<<768, 256, 0, stream>>>(qp, kp, vt, ao);

  // output projection: [4096][960] = attn @ Wproj^T + b (fp32 out)
  gemm_bt<1><<<dim3(32, 8), 256, 0, stream>>>(ao, wprojb, bproj, out, 960, 1024, 960);
}

// Round 7
// 172.399 us; speedup vs baseline: 2.5018x; 1.4045x over previous
//
#include <hip/hip_runtime.h>
#include <cstdint>
#include <cstddef>

// Problem constants: B=2, T=2048, C=960, NH=24, NKV=6, HD=40
// qkv_out = 1440 (padded to 1536 for GEMM), proj N = 960 (padded to 1024)
// Attention layouts use D padded to 48 (40 real + 8 zero).

#define DI __device__ __forceinline__

typedef _Float16 f16x8 __attribute__((ext_vector_type(8)));
typedef _Float16 f16x4 __attribute__((ext_vector_type(4)));
typedef _Float16 f16x2 __attribute__((ext_vector_type(2)));
typedef float f32x4 __attribute__((ext_vector_type(4)));
typedef unsigned short u16;
typedef unsigned int u32;

DI u16 f2h(float f) { _Float16 h = (_Float16)f; return __builtin_bit_cast(u16, h); }
DI float h2f(u16 u) { return (float)__builtin_bit_cast(_Float16, u); }
DI f16x2 pkrtz(float a, float b) { return __builtin_bit_cast(f16x2, __builtin_amdgcn_cvt_pkrtz(a, b)); }

#define MFMA32(a, b, c) __builtin_amdgcn_mfma_f32_16x16x32_f16(a, b, c, 0, 0, 0)
#define MFMA16(a, b, c) __builtin_amdgcn_mfma_f32_16x16x16f16(a, b, c, 0, 0, 0)

DI void gload_lds16(const void* g, void* l) {
  __builtin_amdgcn_global_load_lds((const __attribute__((address_space(1))) u32*)g,
                                   (__attribute__((address_space(3))) u32*)l, 16, 0, 0);
}

// ---------------- conversion kernels ----------------

__global__ void cvt_x_kernel(const float* __restrict__ x, u16* __restrict__ o, int n4) {
  int i = blockIdx.x * 256 + threadIdx.x;
  if (i >= n4) return;
  float4 v = ((const float4*)x)[i];
  ushort4 r;
  r.x = f2h(v.x); r.y = f2h(v.y); r.z = f2h(v.z); r.w = f2h(v.w);
  ((ushort4*)o)[i] = r;
}

__global__ void cvt_w_kernel(const float* __restrict__ w, const float* __restrict__ bias,
                             u16* __restrict__ o, float* __restrict__ bo,
                             int rows_in, int rows_out, int cols) {
  int i = blockIdx.x * 256 + threadIdx.x;
  int c4 = cols >> 2;
  int total = rows_out * c4;
  if (i < total) {
    int row = i / c4, c = (i - row * c4) * 4;
    ushort4 r;
    if (row < rows_in) {
      float4 v = *(const float4*)&w[(size_t)row * cols + c];
      r.x = f2h(v.x); r.y = f2h(v.y); r.z = f2h(v.z); r.w = f2h(v.w);
    } else {
      r.x = r.y = r.z = r.w = 0;
    }
    *(ushort4*)&o[(size_t)row * cols + c] = r;
  }
  if (bo != nullptr && i < rows_out) bo[i] = (i < rows_in) ? bias[i] : 0.f;
}

// ---------------- GEMM: C[M][N] = A[M][K] @ B[N][K]^T + bias ----------------
template <int MODE>
__global__ __launch_bounds__(256) void gemm_bt(const u16* __restrict__ A, const u16* __restrict__ Bw,
                                               const float* __restrict__ bias, void* __restrict__ outp,
                                               int K, int Npad, int Nstore) {
  __shared__ u16 As[128 * 32];
  __shared__ u16 Bs[128 * 32];
  const int tid = threadIdx.x;
  const int l = tid & 63, w = tid >> 6;
  const int bm = blockIdx.x, bn = blockIdx.y;
  const int wm = w >> 1, wn = w & 1;
  const int la = l & 15, lg = l >> 4;

  const u16* ga = A + (size_t)(bm * 128 + (tid >> 2)) * K + (tid & 3) * 8;
  const u16* gb = Bw + (size_t)(bn * 128 + (tid >> 2)) * K + (tid & 3) * 8;
  void* lA = (void*)(As + (size_t)w * 512);
  void* lB = (void*)(Bs + (size_t)w * 512);

  f32x4 acc[4][4] = {};

  for (int k0 = 0; k0 < K; k0 += 32) {
    __syncthreads();
    gload_lds16(ga, lA);
    gload_lds16(ga + (size_t)64 * K, (char*)lA + 4096);
    gload_lds16(gb, lB);
    gload_lds16(gb + (size_t)64 * K, (char*)lB + 4096);
    ga += 32; gb += 32;
    __syncthreads();
    f16x8 af[4], bf[4];
#pragma unroll
    for (int i = 0; i < 4; i++)
      af[i] = *(const f16x8*)&As[(wm * 64 + i * 16 + la) * 32 + lg * 8];
#pragma unroll
    for (int j = 0; j < 4; j++)
      bf[j] = *(const f16x8*)&Bs[(wn * 64 + j * 16 + la) * 32 + lg * 8];
#pragma unroll
    for (int i = 0; i < 4; i++)
#pragma unroll
      for (int j = 0; j < 4; j++)
        acc[i][j] = MFMA32(af[i], bf[j], acc[i][j]);
  }

  const int rowb = bm * 128 + wm * 64 + lg * 4;
  const int colb = bn * 128 + wn * 64 + la;
#pragma unroll
  for (int j = 0; j < 4; j++) {
    int col = colb + j * 16;
    float bv = (MODE == 1 && col >= Nstore) ? 0.f : bias[col];
#pragma unroll
    for (int i = 0; i < 4; i++) {
#pragma unroll
      for (int r = 0; r < 4; r++) {
        int row = rowb + i * 16 + r;
        float v = acc[i][j][r] + bv;
        if (MODE == 0) {
          ((u16*)outp)[(size_t)row * Npad + col] = f2h(v);
        } else {
          if (col < Nstore) ((float*)outp)[(size_t)row * Nstore + col] = v;
        }
      }
    }
  }
}

// ---------------- RoPE + scatter ----------------
__global__ __launch_bounds__(256) void rope_scatter(const u16* __restrict__ qkv,
                                                    u16* __restrict__ qp, u16* __restrict__ kp,
                                                    u16* __restrict__ vt) {
  const int m = blockIdx.x;  // b*2048 + t
  const int b = m >> 11, t = m & 2047;
  const size_t qkvrow = (size_t)m * 1536;
  for (int i = threadIdx.x; i < 864; i += 256) {
    if (i < 720) {
      int head = i / 24, pp = i - head * 24;  // 30 heads x 24 pair-slots (48 dims)
      bool isq = head < 24;
      int hh = isq ? head : head - 24;
      u16* dst = isq ? (qp + (((size_t)b * 24 + hh) * 2048 + t) * 48)
                     : (kp + (((size_t)b * 6 + hh) * 2048 + t) * 48);
      if (pp < 20) {
        int col = isq ? (head * 40 + 2 * pp) : (960 + hh * 40 + 2 * pp);
        float x1 = h2f(qkv[qkvrow + col]);
        float x2 = h2f(qkv[qkvrow + col + 1]);
        float inv = powf(10000.f, -(float)pp * 0.05f);  // 10000^(-2*pp/40)
        float th = (float)t * inv;
        float sn = sinf(th), cs = cosf(th);
        float r1 = x1 * cs - x2 * sn;
        float r2 = x1 * sn + x2 * cs;
        if (isq) { r1 *= 0.2281099142f; r2 *= 0.2281099142f; }  // log2e / sqrt(40)
        dst[2 * pp] = f2h(r1);
        dst[2 * pp + 1] = f2h(r2);
      } else {
        dst[2 * pp] = 0;
        dst[2 * pp + 1] = 0;
      }
    } else {
      int j = i - 720;  // 6 heads x 24 pair-slots of V^T
      int head = j / 24, pp = j - head * 24;
      size_t vb = (((size_t)b * 6 + head) * 48 + 2 * pp) * 2048 + t;
      if (pp < 20) {
        int col = 1200 + head * 40 + 2 * pp;
        vt[vb] = qkv[qkvrow + col];
        vt[vb + 2048] = qkv[qkvrow + col + 1];
      } else {
        vt[vb] = 0;
        vt[vb + 2048] = 0;
      }
    }
  }
}

// ---------------- flash attention (causal, GQA) ----------------
// Wave = 2 q-heads (GQA pair) x 16 q-rows, processing window pair {127-wp, wp}
// sequentially (equal total work per wave -> no CU imbalance, no drain tail),
// with the kv range of each window SPLIT in 2 across sibling waves; partials
// (m, per-lane l, acc) merged through LDS. K register double-buffered; exactly
// one masked chunk; deferred per-lane lsum (no sum-shfl in the chunk chain);
// exp2-domain softmax with defer-max. XCD-swizzled block id for K/V L2 locality.
__global__ __launch_bounds__(256, 4) void attn_kernel(const u16* __restrict__ qp,
                                                      const u16* __restrict__ kp,
                                                      const u16* __restrict__ vt,
                                                      u16* __restrict__ ao) {
  __shared__ float smem[2][64][29];  // [head-pair][lane][12 accA,12 accB, mA,lA,mB,lB]
  const int tid = threadIdx.x, l = tid & 63, wv = tid >> 6;
  const int la = l & 15, lg = l >> 4;
  const int orig = blockIdx.x;
  const int vbid = (orig & 7) * 96 + (orig >> 3);  // XCD-concentrating swizzle (768=8*96)
  const int bhk = vbid >> 6, wp = vbid & 63;
  const int b = bhk / 6, hk = bhk - b * 6;
  const int hp = wv >> 1, half = wv & 1;
  const int h0 = hk * 4 + hp * 2;

  const u16* kg = kp + ((size_t)b * 6 + hk) * 2048 * 48;
  const u16* vg = vt + ((size_t)b * 6 + hk) * 48 * 2048;

  for (int wi = 0; wi < 2; ++wi) {
    const int w = wi ? wp : 127 - wp;
    const int q0 = w * 16, qg = q0 + la;

    const u16* qra = qp + (((size_t)b * 24 + h0) * 2048 + qg) * 48;
    const u16* qrb = qra + (size_t)2048 * 48;
    f16x8 qa8 = *(const f16x8*)(qra + lg * 8);
    f16x4 qa4 = *(const f16x4*)(qra + 32 + lg * 4);
    f16x8 qb8 = *(const f16x8*)(qrb + lg * 8);
    f16x4 qb4 = *(const f16x4*)(qrb + 32 + lg * 4);

    f32x4 accA0 = {}, accA1 = {}, accA2 = {};
    f32x4 accB0 = {}, accB1 = {}, accB2 = {};
    float mA = -1e30f, mB = -1e30f, lsA = 0.f, lsB = 0.f;
    const int nch = (w >> 1) + 1;
    const int cmid = (nch + 1) >> 1;
    const int c0 = half ? cmid : 0;
    const int c1 = half ? nch : cmid;
    const bool lastmask = (c1 == nch) && (c1 > c0);

    f16x8 kA08, kA18, kB08, kB18;
    f16x4 kA04, kA14, kB04, kB14;

#define LOADK(P, c) do { \
    const u16* kr0_ = kg + ((size_t)((c) * 32) + la) * 48; \
    P##08 = *(const f16x8*)(kr0_ + lg * 8); \
    P##04 = *(const f16x4*)(kr0_ + 32 + lg * 4); \
    const u16* kr1_ = kr0_ + 16 * 48; \
    P##18 = *(const f16x8*)(kr1_ + lg * 8); \
    P##14 = *(const f16x4*)(kr1_ + 32 + lg * 4); \
  } while (0)

#define SOFTMAX(s0, s1, mrun, lrun, a0, a1, a2, p0, p1) do { \
    float pm_ = fmaxf(fmaxf(fmaxf(s0[0], s0[1]), fmaxf(s0[2], s0[3])), \
                      fmaxf(fmaxf(s1[0], s1[1]), fmaxf(s1[2], s1[3]))); \
    pm_ = fmaxf(pm_, __shfl_xor(pm_, 16)); \
    pm_ = fmaxf(pm_, __shfl_xor(pm_, 32)); \
    if (!__all(pm_ <= mrun + 5.f)) { \
      float mn_ = fmaxf(mrun, pm_); \
      float al_ = exp2f(mrun - mn_); \
      mrun = mn_; lrun *= al_; \
      _Pragma("unroll") for (int r = 0; r < 4; r++) { a0[r] *= al_; a1[r] *= al_; a2[r] *= al_; } \
    } \
    _Pragma("unroll") for (int r = 0; r < 4; r++) { \
      s0[r] = exp2f(s0[r] - mrun); s1[r] = exp2f(s1[r] - mrun); lrun += s0[r] + s1[r]; } \
    p0 = __builtin_shufflevector(pkrtz(s0[0], s0[1]), pkrtz(s0[2], s0[3]), 0, 1, 2, 3); \
    p1 = __builtin_shufflevector(pkrtz(s1[0], s1[1]), pkrtz(s1[2], s1[3]), 0, 1, 2, 3); \
  } while (0)

#define COMPUTE(P, c, MASKED) do { \
    const int kv0_ = (c) * 32; \
    const u16* vb_ = vg + (size_t)la * 2048 + kv0_ + lg * 4; \
    f16x4 v00 = *(const f16x4*)(vb_); \
    f16x4 v01 = *(const f16x4*)(vb_ + 16); \
    f16x4 v10 = *(const f16x4*)(vb_ + (size_t)16 * 2048); \
    f16x4 v11 = *(const f16x4*)(vb_ + (size_t)16 * 2048 + 16); \
    f16x4 v20 = *(const f16x4*)(vb_ + (size_t)32 * 2048); \
    f16x4 v21 = *(const f16x4*)(vb_ + (size_t)32 * 2048 + 16); \
    f32x4 z_ = {0.f, 0.f, 0.f, 0.f}; \
    f32x4 sA0 = MFMA32(P##08, qa8, z_); sA0 = MFMA16(P##04, qa4, sA0); \
    f32x4 sA1 = MFMA32(P##18, qa8, z_); sA1 = MFMA16(P##14, qa4, sA1); \
    f32x4 sB0 = MFMA32(P##08, qb8, z_); sB0 = MFMA16(P##04, qb4, sB0); \
    f32x4 sB1 = MFMA32(P##18, qb8, z_); sB1 = MFMA16(P##14, qb4, sB1); \
    if (MASKED) { \
      _Pragma("unroll") for (int r = 0; r < 4; r++) { \
        int kva_ = kv0_ + lg * 4 + r; \
        if (kva_ > qg) { sA0[r] = -1e30f; sB0[r] = -1e30f; } \
        if (kva_ + 16 > qg) { sA1[r] = -1e30f; sB1[r] = -1e30f; } \
      } \
    } \
    f16x4 pA0, pA1, pB0, pB1; \
    SOFTMAX(sA0, sA1, mA, lsA, accA0, accA1, accA2, pA0, pA1); \
    SOFTMAX(sB0, sB1, mB, lsB, accB0, accB1, accB2, pB0, pB1); \
    accA0 = MFMA16(v00, pA0, accA0); accA0 = MFMA16(v01, pA1, accA0); \
    accA1 = MFMA16(v10, pA0, accA1); accA1 = MFMA16(v11, pA1, accA1); \
    accA2 = MFMA16(v20, pA0, accA2); accA2 = MFMA16(v21, pA1, accA2); \
    accB0 = MFMA16(v00, pB0, accB0); accB0 = MFMA16(v01, pB1, accB0); \
    accB1 = MFMA16(v10, pB0, accB1); accB1 = MFMA16(v11, pB1, accB1); \
    accB2 = MFMA16(v20, pB0, accB2); accB2 = MFMA16(v21, pB1, accB2); \
  } while (0)

    if (c1 > c0) {
      int c = c0;
      LOADK(kA, c0);
      for (; c + 2 < c1; c += 2) {
        LOADK(kB, c + 1);
        COMPUTE(kA, c, false);
        LOADK(kA, c + 2);
        COMPUTE(kB, c + 1, false);
      }
      if (c + 2 == c1) {
        LOADK(kB, c + 1);
        COMPUTE(kA, c, false);
        COMPUTE(kB, c + 1, lastmask);
      } else {
        COMPUTE(kA, c, lastmask);
      }
    }
#undef LOADK
#undef SOFTMAX
#undef COMPUTE

    // reduce per-lane lsum over the 4 lg groups (la fixed)
    lsA += __shfl_xor(lsA, 16); lsA += __shfl_xor(lsA, 32);
    lsB += __shfl_xor(lsB, 16); lsB += __shfl_xor(lsB, 32);

    float* sl = &smem[hp][l][0];
    if (half) {
#pragma unroll
      for (int r = 0; r < 4; r++) {
        sl[r] = accA0[r]; sl[4 + r] = accA1[r]; sl[8 + r] = accA2[r];
        sl[12 + r] = accB0[r]; sl[16 + r] = accB1[r]; sl[20 + r] = accB2[r];
      }
      sl[24] = mA; sl[25] = lsA; sl[26] = mB; sl[27] = lsB;
    }
    __syncthreads();
    if (!half) {
      u16* orow = ao + ((size_t)b * 2048 + qg) * 960 + h0 * 40;
      {
        float mm = sl[24], ml = sl[25];
        float M = fmaxf(mA, mm);
        float e0 = exp2f(mA - M), e1 = exp2f(mm - M);
        float L = lsA * e0 + ml * e1;
        float f0 = e0 / L, f1 = e1 / L;
        f16x4 o0 = __builtin_shufflevector(
            pkrtz(accA0[0] * f0 + sl[0] * f1, accA0[1] * f0 + sl[1] * f1),
            pkrtz(accA0[2] * f0 + sl[2] * f1, accA0[3] * f0 + sl[3] * f1), 0, 1, 2, 3);
        f16x4 o1 = __builtin_shufflevector(
            pkrtz(accA1[0] * f0 + sl[4] * f1, accA1[1] * f0 + sl[5] * f1),
            pkrtz(accA1[2] * f0 + sl[6] * f1, accA1[3] * f0 + sl[7] * f1), 0, 1, 2, 3);
        f16x4 o2 = __builtin_shufflevector(
            pkrtz(accA2[0] * f0 + sl[8] * f1, accA2[1] * f0 + sl[9] * f1),
            pkrtz(accA2[2] * f0 + sl[10] * f1, accA2[3] * f0 + sl[11] * f1), 0, 1, 2, 3);
        *(f16x4*)(orow + lg * 4) = o0;
        *(f16x4*)(orow + 16 + lg * 4) = o1;
        if (lg < 2) *(f16x4*)(orow + 32 + lg * 4) = o2;
      }
      {
        float mm = sl[26], ml = sl[27];
        float M = fmaxf(mB, mm);
        float e0 = exp2f(mB - M), e1 = exp2f(mm - M);
        float L = lsB * e0 + ml * e1;
        float f0 = e0 / L, f1 = e1 / L;
        f16x4 o0 = __builtin_shufflevector(
            pkrtz(accB0[0] * f0 + sl[12] * f1, accB0[1] * f0 + sl[13] * f1),
            pkrtz(accB0[2] * f0 + sl[14] * f1, accB0[3] * f0 + sl[15] * f1), 0, 1, 2, 3);
        f16x4 o1 = __builtin_shufflevector(
            pkrtz(accB1[0] * f0 + sl[16] * f1, accB1[1] * f0 + sl[17] * f1),
            pkrtz(accB1[2] * f0 + sl[18] * f1, accB1[3] * f0 + sl[19] * f1), 0, 1, 2, 3);
        f16x4 o2 = __builtin_shufflevector(
            pkrtz(accB2[0] * f0 + sl[20] * f1, accB2[1] * f0 + sl[21] * f1),
            pkrtz(accB2[2] * f0 + sl[22] * f1, accB2[3] * f0 + sl[23] * f1), 0, 1, 2, 3);
        *(f16x4*)(orow + 40 + lg * 4) = o0;
        *(f16x4*)(orow + 56 + lg * 4) = o1;
        if (lg < 2) *(f16x4*)(orow + 72 + lg * 4) = o2;
      }
    }
    __syncthreads();
  }
}

// ---------------- launch ----------------

extern "C" void kernel_launch(void* const* d_in, const int* in_sizes, int n_in,
                              void* d_out, int out_size, void* d_ws, size_t ws_size,
                              hipStream_t stream) {
  const float* x = (const float*)d_in[0];      // [2][2048][960]
  const float* Wqkv = (const float*)d_in[1];   // [1440][960]
  const float* bqkv = (const float*)d_in[2];   // [1440]
  const float* Wproj = (const float*)d_in[3];  // [960][960]
  const float* bproj = (const float*)d_in[4];  // [960]
  float* out = (float*)d_out;                  // [4096][960] fp32

  // workspace layout (~47 MB)
  char* ws = (char*)d_ws;
  u16* xb = (u16*)ws;                                // 4096*960
  u16* wqkvb = xb + (size_t)4096 * 960;              // 1536*960
  u16* wprojb = wqkvb + (size_t)1536 * 960;          // 1024*960
  float* bqp = (float*)(wprojb + (size_t)1024 * 960);// 1536
  u16* qkvb = (u16*)(bqp + 1536);                    // 4096*1536
  u16* qp = qkvb + (size_t)4096 * 1536;              // 2*24*2048*48
  u16* kp = qp + (size_t)2 * 24 * 2048 * 48;         // 2*6*2048*48
  u16* vt = kp + (size_t)2 * 6 * 2048 * 48;          // 2*6*48*2048
  u16* ao = vt + (size_t)2 * 6 * 48 * 2048;          // 4096*960

  // converts
  cvt_x_kernel<<<3840, 256, 0, stream>>>(x, xb, 4096 * 960 / 4);
  cvt_w_kernel<<<1440, 256, 0, stream>>>(Wqkv, bqkv, wqkvb, bqp, 1440, 1536, 960);
  cvt_w_kernel<<<960, 256, 0, stream>>>(Wproj, nullptr, wprojb, nullptr, 960, 1024, 960);

  // QKV projection: [4096][1536] = x @ Wqkv^T + b
  gemm_bt<0><<<dim3(32, 12), 256, 0, stream>>>(xb, wqkvb, bqp, qkvb, 960, 1536, 1536);

  // RoPE + scatter to attention layouts (D=48)
  rope_scatter<<<4096, 256, 0, stream>>>(qkvb, qp, kp, vt);

  // flash attention: 768 equal-work blocks (12 bhk x 64 window-pairs), 4 waves:
  // 2 head-pairs x 2 kv-halves, merged in LDS
  attn_kernel<<<768, 256, 0, stream>>>(qp, kp, vt, ao);

  // output projection: [4096][960] = attn @ Wproj^T + b (fp32 out)
  gemm_bt<1><<<dim3(32, 8), 256, 0, stream>>>(ao, wprojb, bproj, out, 960, 1024, 960);
}